// Round 1
// baseline (15861.153 us; speedup 1.0000x reference)
//
#include <hip/hip_runtime.h>
#include <hip/hip_bf16.h>
#include <cstdint>

#define S_LEN 512
#define BATCH 64
#define IDIM  1024
#define HDIM  1024
#define G4    4096
#define NBLK  256   // recurrence grid

typedef __attribute__((ext_vector_type(8))) short short8;
typedef __attribute__((ext_vector_type(4))) float f32x4;
typedef __attribute__((ext_vector_type(4))) unsigned short ushort4v;
typedef __attribute__((ext_vector_type(4))) unsigned int uint4v;

__device__ __forceinline__ unsigned short f2bf(float f){
  union { float f; unsigned u; } v; v.f = f;
  unsigned r = (v.u + 0x7fffu + ((v.u >> 16) & 1u)) >> 16;
  return (unsigned short)r;
}
__device__ __forceinline__ float bf2f(unsigned short s){
  union { unsigned u; float f; } v; v.u = ((unsigned)s) << 16;
  return v.f;
}
__device__ __forceinline__ float sigf(float x){ return 1.0f / (1.0f + __expf(-x)); }
__device__ __forceinline__ float tanhf_fast(float x){
  float e = __expf(2.0f * x);
  return 1.0f - 2.0f / (e + 1.0f);
}
__device__ __forceinline__ f32x4 mfma_bf16(short8 a, short8 b, f32x4 c){
  return __builtin_amdgcn_mfma_f32_16x16x32_bf16(a, b, c, 0, 0, 0);
}

// xg packed-load/store helpers (f32 or bf16 storage)
__device__ __forceinline__ f32x4 xg_load(const float* p){ return *reinterpret_cast<const f32x4*>(p); }
__device__ __forceinline__ f32x4 xg_load(const unsigned short* p){
  ushort4v u = *reinterpret_cast<const ushort4v*>(p);
  f32x4 r; r[0]=bf2f(u[0]); r[1]=bf2f(u[1]); r[2]=bf2f(u[2]); r[3]=bf2f(u[3]);
  return r;
}
__device__ __forceinline__ void xg_store(float* p, f32x4 v){ *reinterpret_cast<f32x4*>(p) = v; }
__device__ __forceinline__ void xg_store(unsigned short* p, f32x4 v){
  ushort4v u; u[0]=f2bf(v[0]); u[1]=f2bf(v[1]); u[2]=f2bf(v[2]); u[3]=f2bf(v[3]);
  *reinterpret_cast<ushort4v*>(p) = u;
}

// ---------------------------------------------------------------------------
// prep: pack W_hh into per-block MFMA-B-fragment order (bf16), bias sum, h0->bf16
// Wpack[o], o = ((bk*32 + ks)*64 + l)*8 + e  ->  W_hh[row][k],
//   c=l&15, row = (c>>2)*1024 + bk*4 + (c&3), k = ks*32 + (l>>4)*8 + e
// ---------------------------------------------------------------------------
__global__ __launch_bounds__(256) void prep_kernel(
    const float* __restrict__ Whh, const float* __restrict__ bih,
    const float* __restrict__ bhh, const float* __restrict__ h0,
    unsigned short* __restrict__ Wpack, float* __restrict__ biasSum,
    unsigned short* __restrict__ hA){
  int i = blockIdx.x * 256 + threadIdx.x;
  if (i < G4) biasSum[i] = bih[i] + bhh[i];
  if (i < BATCH*HDIM) hA[i] = f2bf(h0[i]);
  if (i < G4*HDIM){
    int e = i & 7, l = (i >> 3) & 63, ks = (i >> 9) & 31, bk = i >> 14;
    int c = l & 15, q = l >> 4;
    int row = (c >> 2) * HDIM + bk * 4 + (c & 3);
    int k = ks * 32 + q * 8 + e;
    Wpack[i] = f2bf(Whh[row * HDIM + k]);
  }
}

// ---------------------------------------------------------------------------
// x_gates GEMM: out[m][n] = sum_k In[m][k] * Wih[n][k] + biasSum[n]
// M=32768 (s*64+b), N=4096, K=1024. 128x128 tile, BK=64, 4 waves (2x2).
// Writes packed xg[s][bk][c][b], c = (n>>10)*4 + (n&3), bk = (n&1023)>>2.
// ---------------------------------------------------------------------------
template<typename XGT>
__global__ __launch_bounds__(256) void xg_gemm(
    const float* __restrict__ In, const float* __restrict__ Wih,
    const float* __restrict__ biasSum, XGT* __restrict__ xg){
  __shared__ __align__(16) unsigned short Abuf[128 * 72];
  __shared__ __align__(16) unsigned short Bbuf[128 * 72];
  const int bid = blockIdx.x;
  const int tm = bid >> 5, tn = bid & 31;
  const int bm0 = tm * 128, bn0 = tn * 128;
  const int tid = threadIdx.x;
  const int wid = tid >> 6, l = tid & 63;
  const int wm = wid >> 1, wn = wid & 1;
  const int lr = tid >> 4;          // staging row group 0..15
  const int lk = (tid & 15) * 4;    // staging k offset

  f32x4 acc[4][4];
  #pragma unroll
  for (int a = 0; a < 4; ++a)
    #pragma unroll
    for (int b = 0; b < 4; ++b) acc[a][b] = (f32x4){0.f, 0.f, 0.f, 0.f};

  for (int kt = 0; kt < 16; ++kt){
    #pragma unroll
    for (int it = 0; it < 8; ++it){
      int r = lr + it * 16;
      f32x4 a4 = *reinterpret_cast<const f32x4*>(&In[(size_t)(bm0 + r) * IDIM + kt * 64 + lk]);
      ushort4v ab; ab[0]=f2bf(a4[0]); ab[1]=f2bf(a4[1]); ab[2]=f2bf(a4[2]); ab[3]=f2bf(a4[3]);
      *reinterpret_cast<ushort4v*>(&Abuf[r * 72 + lk]) = ab;
      f32x4 b4 = *reinterpret_cast<const f32x4*>(&Wih[(size_t)(bn0 + r) * IDIM + kt * 64 + lk]);
      ushort4v bb; bb[0]=f2bf(b4[0]); bb[1]=f2bf(b4[1]); bb[2]=f2bf(b4[2]); bb[3]=f2bf(b4[3]);
      *reinterpret_cast<ushort4v*>(&Bbuf[r * 72 + lk]) = bb;
    }
    __syncthreads();
    #pragma unroll
    for (int ks = 0; ks < 2; ++ks){
      short8 af[4], bfv[4];
      #pragma unroll
      for (int f = 0; f < 4; ++f){
        af[f]  = *reinterpret_cast<const short8*>(&Abuf[(wm*64 + f*16 + (l & 15)) * 72 + ks*32 + (l >> 4) * 8]);
        bfv[f] = *reinterpret_cast<const short8*>(&Bbuf[(wn*64 + f*16 + (l & 15)) * 72 + ks*32 + (l >> 4) * 8]);
      }
      #pragma unroll
      for (int fm = 0; fm < 4; ++fm)
        #pragma unroll
        for (int fn = 0; fn < 4; ++fn)
          acc[fm][fn] = mfma_bf16(af[fm], bfv[fn], acc[fm][fn]);
    }
    __syncthreads();
  }

  // epilogue: acc[fm][fn][r] -> element (m = bm0+wm*64+fm*16+(l>>4)*4+r,
  //                                      n = bn0+wn*64+fn*16+(l&15))
  const int q = l >> 4, c16 = l & 15;
  #pragma unroll
  for (int fn = 0; fn < 4; ++fn){
    int n = bn0 + wn * 64 + fn * 16 + c16;
    float bias = biasSum[n];
    int bkk = (n & 1023) >> 2;
    int cc = ((n >> 10) << 2) | (n & 3);
    #pragma unroll
    for (int fm = 0; fm < 4; ++fm){
      int m0 = bm0 + wm * 64 + fm * 16 + q * 4;
      int s = m0 >> 6, b0 = m0 & 63;
      f32x4 v = acc[fm][fn];
      v[0] += bias; v[1] += bias; v[2] += bias; v[3] += bias;
      size_t base = (((size_t)s * 256 + bkk) * 16 + cc) * 64 + b0;
      xg_store(&xg[base], v);
    }
  }
}

// ---------------------------------------------------------------------------
// recurrence: 256 persistent blocks, block bk owns h-cols jj = bk*4+{0..3}
// (16 W_hh rows in LDS). Per step: 64x16x1024 MFMA vs h (global ping-pong,
// bf16), gate math + retention in registers, grid barrier.
// ---------------------------------------------------------------------------
template<typename XGT>
__global__ __launch_bounds__(256) void recur_kernel(
    const float* __restrict__ h0, const float* __restrict__ c0,
    const float* __restrict__ ret, const unsigned short* __restrict__ Wpack,
    const XGT* __restrict__ xg, unsigned short* __restrict__ hA,
    unsigned short* __restrict__ hB, float* __restrict__ out,
    float* __restrict__ hc_out, unsigned* __restrict__ counter){
  __shared__ __align__(16) unsigned short Wlds[16384];   // 32 KB: [ks][lane][8]
  __shared__ float gates[64 * 17];                       // padded vs bank conflicts

  const int bk = blockIdx.x;
  const int tid = threadIdx.x;

  // stage this block's W slice (linear copy, conflict-free)
  {
    const uint4v* src = reinterpret_cast<const uint4v*>(Wpack + (size_t)bk * 16384);
    uint4v* dst = reinterpret_cast<uint4v*>(Wlds);
    #pragma unroll
    for (int it = 0; it < 8; ++it) dst[it * 256 + tid] = src[it * 256 + tid];
  }

  const int b = tid >> 2, j = tid & 3, jj = bk * 4 + j;
  float c_reg = c0[b * HDIM + jj];
  float h_reg = h0[b * HDIM + jj];
  float r_reg = ret[jj];

  const int w = tid >> 6, l = tid & 63;
  const int arow = w * 16 + (l & 15);
  const int kq = (l >> 4) * 8;
  const int c16 = l & 15;
  const int b0 = w * 16 + (l >> 4) * 4;

  __syncthreads();

  for (int s = 0; s < S_LEN; ++s){
    const unsigned short* cur = (s & 1) ? hB : hA;
    unsigned short* nxt = (s & 1) ? hA : hB;

    f32x4 acc = (f32x4){0.f, 0.f, 0.f, 0.f};
    const unsigned short* ap = cur + (size_t)arow * HDIM + kq;
    #pragma unroll 8
    for (int ks = 0; ks < 32; ++ks){
      short8 a = *reinterpret_cast<const short8*>(ap + ks * 32);
      short8 bw = *reinterpret_cast<const short8*>(&Wlds[ks * 512 + l * 8]);
      acc = mfma_bf16(a, bw, acc);
    }
    // add packed x_gates, stash to LDS for the update phase
    {
      size_t xbase = (((size_t)s * 256 + bk) * 16 + c16) * 64 + b0;
      f32x4 xv = xg_load(&xg[xbase]);
      #pragma unroll
      for (int r = 0; r < 4; ++r)
        gates[(b0 + r) * 17 + c16] = acc[r] + xv[r];
    }
    __syncthreads();

    // gate math + retention filter; c,h live in registers of thread (b,j)
    {
      float gi = gates[b * 17 + j];
      float gf = gates[b * 17 + 4 + j];
      float gg = gates[b * 17 + 8 + j];
      float go = gates[b * 17 + 12 + j];
      float ig = sigf(gi), fg = sigf(gf), gt = tanhf_fast(gg), og = sigf(go);
      float cy = fg * c_reg + ig * gt;
      float hy = og * tanhf_fast(cy);
      hy = r_reg * h_reg + (1.0f - r_reg) * hy;
      c_reg = cy; h_reg = hy;
      nxt[b * HDIM + jj] = f2bf(hy);
      out[((size_t)s * BATCH + b) * HDIM + jj] = hy;
    }

    // grid barrier (device-scope; handles cross-XCD L2 non-coherence)
    __syncthreads();
    if (tid == 0){
      __threadfence();  // write back this XCD's dirty L2 (all waves' h stores)
      __hip_atomic_fetch_add(counter, 1u, __ATOMIC_RELEASE, __HIP_MEMORY_SCOPE_AGENT);
      unsigned tgt = (unsigned)(s + 1) * NBLK;
      unsigned spins = 0;
      while (__hip_atomic_load(counter, __ATOMIC_RELAXED, __HIP_MEMORY_SCOPE_AGENT) < tgt){
        __builtin_amdgcn_s_sleep(1);
        if (++spins > 400000000u) break;   // safety bailout, never expected
      }
      __threadfence();  // acquire: invalidate stale L1/L2 before reading new h
    }
    __syncthreads();
  }

  hc_out[b * HDIM + jj] = h_reg;                     // final h
  hc_out[BATCH * HDIM + b * HDIM + jj] = c_reg;      // final c
}

// ---------------------------------------------------------------------------
extern "C" void kernel_launch(void* const* d_in, const int* in_sizes, int n_in,
                              void* d_out, int out_size, void* d_ws, size_t ws_size,
                              hipStream_t stream){
  const float* In  = (const float*)d_in[0];
  const float* h0  = (const float*)d_in[1];
  const float* c0  = (const float*)d_in[2];
  const float* Wih = (const float*)d_in[3];
  const float* Whh = (const float*)d_in[4];
  const float* bih = (const float*)d_in[5];
  const float* bhh = (const float*)d_in[6];
  const float* ret = (const float*)d_in[7];
  float* out = (float*)d_out;

  char* ws = (char*)d_ws;
  const size_t off_cnt  = 0;
  const size_t off_bias = 256;
  const size_t off_hA   = 16640;                  // 256+16384, 256-aligned
  const size_t off_hB   = off_hA + 131072;
  const size_t off_wp   = off_hB + 131072;
  const size_t off_xg   = off_wp + 8388608;
  const size_t xg_elems = (size_t)S_LEN * G4 * BATCH;
  const size_t need_f32 = off_xg + xg_elems * 4;
  const size_t need_b16 = off_xg + xg_elems * 2;

  unsigned*       counter = (unsigned*)(ws + off_cnt);
  float*          biasSum = (float*)(ws + off_bias);
  unsigned short* hA      = (unsigned short*)(ws + off_hA);
  unsigned short* hB      = (unsigned short*)(ws + off_hB);
  unsigned short* Wpack   = (unsigned short*)(ws + off_wp);

  if (ws_size < need_b16) return;  // cannot run; fail validation loudly

  (void)hipMemsetAsync(ws + off_cnt, 0, 256, stream);
  prep_kernel<<<16384, 256, 0, stream>>>(Whh, bih, bhh, h0, Wpack, biasSum, hA);

  float* hc_out = out + (size_t)S_LEN * BATCH * HDIM;
  if (ws_size >= need_f32){
    float* xg = (float*)(ws + off_xg);
    xg_gemm<float><<<8192, 256, 0, stream>>>(In, Wih, biasSum, xg);
    recur_kernel<float><<<NBLK, 256, 0, stream>>>(h0, c0, ret, Wpack, xg, hA, hB,
                                                  out, hc_out, counter);
  } else {
    unsigned short* xg = (unsigned short*)(ws + off_xg);
    xg_gemm<unsigned short><<<8192, 256, 0, stream>>>(In, Wih, biasSum, xg);
    recur_kernel<unsigned short><<<NBLK, 256, 0, stream>>>(h0, c0, ret, Wpack, xg,
                                                           hA, hB, out, hc_out, counter);
  }
}